// Round 6
// baseline (473.614 us; speedup 1.0000x reference)
//
#include <hip/hip_runtime.h>
#include <hip/hip_bf16.h>
#include <hip/hip_cooperative_groups.h>

namespace cg = cooperative_groups;

// Problem constants
#define BB    8
#define NBB   1024
#define KK    9
#define CC    32
#define CMM   128
#define NTOT  (BB*NBB)        // 8192
#define MM    (NBB*KK)        // 9216 per batch
#define MS    16              // K-split ways
#define MR    (MM/MS)         // 576 m per split
#define NEG   0.01f
#define EPS   1e-5f
#define L2C   (-2.8853900817779268f)   /* -2*log2(e) */

// Workspace layout (floats)
#define OFF_CWT   0
#define SZ_CWT    (BB*CC*MM/2)            // bf16 in float-slots: 1179648
#define OFF_CFX   (OFF_CWT + SZ_CWT)
#define OFF_CFY   (OFF_CFX + BB*MM)
#define OFF_CF0   (OFF_CFY + BB*MM)
#define OFF_PART  (OFF_CF0 + BB*MM)
#define SZ_ONE    (NTOT*CC)               // 262144
#define SZ_PART   (MS*SZ_ONE)
// aliases into dead partial slots (partials consumed in phase L before reuse)
#define OFF_X0    (OFF_PART)              // slot 0 (same-thread RAW in L)
#define OFF_X     (OFF_PART + SZ_ONE)     // slot 1 (written in M1)
#define OFF_H0    (OFF_PART + 2*SZ_ONE)   // slots 2..5 (written in M1)
#define OFF_ST    (OFF_PART + SZ_PART)    // s1[64] then s2[256]

typedef __attribute__((ext_vector_type(8))) short short8;
typedef __attribute__((ext_vector_type(4))) float f32x4;
typedef __attribute__((ext_vector_type(2))) float f32x2;

static __device__ __forceinline__ unsigned short f2bf_rne(float f) {
    __hip_bfloat16 h = __float2bfloat16(f);
    return *reinterpret_cast<unsigned short*>(&h);
}

// ---------------------------------------------------------------------------
// Phased kernel. mode==-1: cooperative, all phases with grid.sync.
// mode==k (0..4): run only phase k (plain launch fallback, 5 dispatches).
// All phases are grid-stride -> correct for ANY grid size.
// Phases: P(prep+convw+zero) | S(MFMA sample) | L(leaky+s1) | M1 | M2.
// Max LDS = 1344 floats (5.4 KB) -> occupancy VGPR-bound only.
// ---------------------------------------------------------------------------
__global__ __launch_bounds__(256, 4) void k_fused(
        const float* __restrict__ pos,  const float* __restrict__ wts,
        const float* __restrict__ kpos, const float* __restrict__ kw,
        const float* __restrict__ cgm,  const float* __restrict__ cbt,
        const float* __restrict__ W1,   const float* __restrict__ b1,
        const float* __restrict__ bg,   const float* __restrict__ bb,
        const float* __restrict__ W2,   const float* __restrict__ b2v,
        float* __restrict__ ws,         float* __restrict__ out,
        int mode) {
    __shared__ __align__(16) float smf[1344];

    short* cwT = (short*)(ws + OFF_CWT);
    float* cfx = ws + OFF_CFX;
    float* cfy = ws + OFF_CFY;
    float* cf0 = ws + OFF_CF0;
    float* part = ws + OFF_PART;
    float* x0 = ws + OFF_X0;
    float* x  = ws + OFF_X;
    float* h0 = ws + OFF_H0;
    float* s1 = ws + OFF_ST;
    float* s2 = ws + OFF_ST + 64;

    int blk = blockIdx.x;
    int gdim = gridDim.x;
    int t = threadIdx.x;

    // ================= Phase P: convw (u<128) + prep (128..415) + zero ======
    if (mode <= 0) {
        for (int u = blk; u < 417; u += gdim) {
            if (u < 128) {
                int l = t & 63, wv = t >> 6;
                int lane15 = l & 15, quad = l >> 4;
                int b = u >> 4, nbl = u & 15;
                int n = b*NBB + nbl*64 + wv*16 + lane15;
                f32x4 w0 = *(const f32x4*)&wts[(size_t)n*CC + quad*8];
                f32x4 w1 = *(const f32x4*)&wts[(size_t)n*CC + quad*8 + 4];
                union { unsigned short us[8]; short8 s; } bfr;
                bfr.us[0] = f2bf_rne(w0.x); bfr.us[1] = f2bf_rne(w0.y);
                bfr.us[2] = f2bf_rne(w0.z); bfr.us[3] = f2bf_rne(w0.w);
                bfr.us[4] = f2bf_rne(w1.x); bfr.us[5] = f2bf_rne(w1.y);
                bfr.us[6] = f2bf_rne(w1.z); bfr.us[7] = f2bf_rne(w1.w);
                // dst includes this lane's n: element = c*MM + n_loc*9 + kk
                short* dst = cwT + (size_t)b*CC*MM
                           + (size_t)(nbl*64 + wv*16 + lane15)*9;
                for (int kk = 0; kk < KK; ++kk) {
                    #pragma unroll
                    for (int ct = 0; ct < 2; ++ct) {
                        int c = ct*16 + lane15;
                        union { unsigned short us[8]; short8 s; } afr;
                        #pragma unroll
                        for (int j = 0; j < 8; ++j)
                            afr.us[j] = f2bf_rne(kw[(size_t)(kk*CC + quad*8 + j)*CC + c]);
                        f32x4 acc = __builtin_amdgcn_mfma_f32_16x16x32_bf16(
                            afr.s, bfr.s, (f32x4)0.f, 0, 0, 0);
                        #pragma unroll
                        for (int reg = 0; reg < 4; ++reg) {
                            int cr = ct*16 + quad*4 + reg;
                            dst[(size_t)cr*MM + kk] = (short)f2bf_rne(acc[reg]);
                        }
                    }
                }
            } else if (u < 416) {
                int gid = (u - 128)*256 + t;      // 0 .. 73727 = BB*MM
                int b = gid / MM;
                int m = gid - b*MM;
                int np = m / 9, k9 = m - np*9;
                float qx = pos[((size_t)(b*NBB + np))*2 + 0] + kpos[k9*2 + 0];
                float qy = pos[((size_t)(b*NBB + np))*2 + 1] + kpos[k9*2 + 1];
                cfx[gid] = -2.f*L2C*qx;
                cfy[gid] = -2.f*L2C*qy;
                cf0[gid] = L2C*(qx*qx + qy*qy);
            } else {
                if (t < 320) s1[t] = 0.f;         // zeroes s1[64] + s2[256]
            }
        }
    }
    if (mode < 0) cg::this_grid().sync();

    // ================= Phase S: MFMA Gaussian-gather ========================
    if (mode < 0 || mode == 1) {
        int l = t & 63, w = t >> 6;
        int lane15 = l & 15, quad = l >> 4;
        for (int u = blk; u < 1024; u += gdim) {
            int ks = u & 15, nb = (u >> 4) & 7, b = u >> 7;
            int nbase = b*NBB + nb*128 + w*32;

            float px[2], py[2], cn[2];
            #pragma unroll
            for (int nt = 0; nt < 2; ++nt) {
                int n = nbase + nt*16 + lane15;
                float X = pos[(size_t)n*2], Y = pos[(size_t)n*2 + 1];
                px[nt] = X; py[nt] = Y; cn[nt] = L2C*(X*X + Y*Y);
            }
            f32x4 acc[2][2];
            #pragma unroll
            for (int nt = 0; nt < 2; ++nt) { acc[nt][0] = (f32x4)0.f; acc[nt][1] = (f32x4)0.f; }

            const float* bx = cfx + (size_t)b*MM;
            const float* by = cfy + (size_t)b*MM;
            const float* b0 = cf0 + (size_t)b*MM;
            const short* ca0 = cwT + (size_t)b*CC*MM + (size_t)lane15*MM;
            const short* ca1 = ca0 + (size_t)16*MM;

            int m0 = ks*MR + quad*8;
            #pragma unroll 2
            for (int kk = 0; kk < MR/32; ++kk, m0 += 32) {
                short8 a0 = *(const short8*)&ca0[m0];
                short8 a1 = *(const short8*)&ca1[m0];
                f32x4 vx0 = *(const f32x4*)&bx[m0];
                f32x4 vx1 = *(const f32x4*)&bx[m0 + 4];
                f32x4 vy0 = *(const f32x4*)&by[m0];
                f32x4 vy1 = *(const f32x4*)&by[m0 + 4];
                f32x4 v00 = *(const f32x4*)&b0[m0];
                f32x4 v01 = *(const f32x4*)&b0[m0 + 4];
                #pragma unroll
                for (int nt = 0; nt < 2; ++nt) {
                    f32x2 Xv = {px[nt], px[nt]};
                    f32x2 Yv = {py[nt], py[nt]};
                    f32x2 Cv = {cn[nt], cn[nt]};
                    f32x2 t0 = (f32x2){v00.x, v00.y} + Cv;
                    t0 = (f32x2){vy0.x, vy0.y}*Yv + t0;
                    t0 = (f32x2){vx0.x, vx0.y}*Xv + t0;
                    f32x2 t1 = (f32x2){v00.z, v00.w} + Cv;
                    t1 = (f32x2){vy0.z, vy0.w}*Yv + t1;
                    t1 = (f32x2){vx0.z, vx0.w}*Xv + t1;
                    f32x2 t2 = (f32x2){v01.x, v01.y} + Cv;
                    t2 = (f32x2){vy1.x, vy1.y}*Yv + t2;
                    t2 = (f32x2){vx1.x, vx1.y}*Xv + t2;
                    f32x2 t3 = (f32x2){v01.z, v01.w} + Cv;
                    t3 = (f32x2){vy1.z, vy1.w}*Yv + t3;
                    t3 = (f32x2){vx1.z, vx1.w}*Xv + t3;
                    float e0 = __builtin_amdgcn_exp2f(t0.x);
                    float e1 = __builtin_amdgcn_exp2f(t0.y);
                    float e2 = __builtin_amdgcn_exp2f(t1.x);
                    float e3 = __builtin_amdgcn_exp2f(t1.y);
                    float e4 = __builtin_amdgcn_exp2f(t2.x);
                    float e5 = __builtin_amdgcn_exp2f(t2.y);
                    float e6 = __builtin_amdgcn_exp2f(t3.x);
                    float e7 = __builtin_amdgcn_exp2f(t3.y);
                    union { unsigned int uu[4]; short8 s; } bf;
                    bf.uu[0] = (__float_as_uint(e0) >> 16) | (__float_as_uint(e1) & 0xffff0000u);
                    bf.uu[1] = (__float_as_uint(e2) >> 16) | (__float_as_uint(e3) & 0xffff0000u);
                    bf.uu[2] = (__float_as_uint(e4) >> 16) | (__float_as_uint(e5) & 0xffff0000u);
                    bf.uu[3] = (__float_as_uint(e6) >> 16) | (__float_as_uint(e7) & 0xffff0000u);
                    acc[nt][0] = __builtin_amdgcn_mfma_f32_16x16x32_bf16(a0, bf.s, acc[nt][0], 0, 0, 0);
                    acc[nt][1] = __builtin_amdgcn_mfma_f32_16x16x32_bf16(a1, bf.s, acc[nt][1], 0, 0, 0);
                }
            }
            #pragma unroll
            for (int nt = 0; nt < 2; ++nt) {
                int n = nbase + nt*16 + lane15;
                #pragma unroll
                for (int ct = 0; ct < 2; ++ct) {
                    int c = ct*16 + quad*4;
                    *(f32x4*)&part[((size_t)ks*NTOT + n)*CC + c] = acc[nt][ct];
                }
            }
        }
    }
    if (mode < 0) cg::this_grid().sync();

    // ================= Phase L: x0 = leaky(sum parts); s1 atomics ===========
    if (mode < 0 || mode == 2) {
        float* red = smf;   // 64 floats
        for (int u = blk; u < 1024; u += gdim) {
            if (t < 64) red[t] = 0.f;
            __syncthreads();
            int idx = u*256 + t;        // covers 262144 = NTOT*CC
            float v = 0.f;
            #pragma unroll
            for (int s = 0; s < MS; ++s) v += part[(size_t)s*SZ_ONE + idx];
            v = v >= 0.f ? v : NEG*v;
            x0[idx] = v;                // aliases slot 0: same-thread RAW, safe
            int c = t & 31;
            atomicAdd(&red[c], v);
            atomicAdd(&red[32 + c], v*v);
            __syncthreads();
            if (t < 64) atomicAdd(&s1[t], red[t]);
            __syncthreads();
        }
    }
    if (mode < 0) cg::this_grid().sync();

    // ================= Phase M1: bn1 + x + MLP1 + h0 + s2 ===================
    if (mode < 0 || mode == 3) {
        float* xrow = smf;          // 8*32
        float* st2  = smf + 256;    // 256
        for (int u = blk; u < 1024; u += gdim) {
            int r = t >> 5, c = t & 31;
            int n0 = u*8;
            {
                int n = n0 + r;
                float mu  = s1[c] * (1.f/NTOT);
                float var = s1[32+c]*(1.f/NTOT) - mu*mu;
                float a   = cgm[c] * rsqrtf(var + EPS);
                float v   = x0[(size_t)n*CC + c];
                v = a*(v - mu) + cbt[c] + wts[(size_t)n*CC + c];
                xrow[r*32 + c] = v;
                x[(size_t)n*CC + c] = v;
            }
            st2[t] = 0.f;
            __syncthreads();
            int j = t & 127, rh = t >> 7;
            float acc4[4];
            #pragma unroll
            for (int q = 0; q < 4; ++q) acc4[q] = b1[j];
            #pragma unroll 4
            for (int cc2 = 0; cc2 < 32; ++cc2) {
                float w1c = W1[cc2*CMM + j];      // coalesced across lanes
                #pragma unroll
                for (int q = 0; q < 4; ++q)
                    acc4[q] = fmaf(xrow[(rh*4 + q)*32 + cc2], w1c, acc4[q]);
            }
            float ls = 0.f, lq = 0.f;
            #pragma unroll
            for (int q = 0; q < 4; ++q) {
                float h = acc4[q] >= 0.f ? acc4[q] : NEG*acc4[q];
                h0[(size_t)(n0 + rh*4 + q)*CMM + j] = h;
                ls += h; lq = fmaf(h, h, lq);
            }
            atomicAdd(&st2[j], ls);
            atomicAdd(&st2[128 + j], lq);
            __syncthreads();
            atomicAdd(&s2[t], st2[t]);            // t covers sum[128]+sq[128]
            __syncthreads();
        }
    }
    if (mode < 0) cg::this_grid().sync();

    // ================= Phase M2: bn2 + MLP2 + outputs =======================
    if (mode < 0 || mode == 4) {
        float* hl   = smf;              // 8*132 padded
        float* mlpd = smf + 8*132;      // 8*34
        for (int u = blk; u < 1024; u += gdim) {
            int n0 = u*8;
            #pragma unroll
            for (int i = 0; i < 4; ++i) {
                int idx = i*256 + t;
                int j = idx & 127, r = idx >> 7;
                float v = h0[(size_t)(n0 + r)*CMM + j];
                float mu  = s2[j] * (1.f/NTOT);
                float var = s2[CMM+j]*(1.f/NTOT) - mu*mu;
                float a   = bg[j] * rsqrtf(var + EPS);
                hl[r*132 + j] = a*(v - mu) + bb[j];
            }
            __syncthreads();
            int r = t >> 5, lane = t & 31;
            float acc0 = b2v[lane];
            float acc1 = (lane < 2) ? b2v[32 + lane] : 0.f;
            for (int j = 0; j < CMM; ++j) {
                float h = hl[r*132 + j];
                acc0 = fmaf(h, W2[(size_t)j*34 + lane], acc0);
                if (lane < 2) acc1 = fmaf(h, W2[(size_t)j*34 + 32 + lane], acc1);
            }
            mlpd[r*34 + lane] = acc0;
            if (lane < 2) mlpd[r*34 + 32 + lane] = acc1;
            __syncthreads();
            int n = n0 + r;
            if (lane < 2)
                out[(size_t)n*2 + lane] = pos[(size_t)n*2 + lane] + mlpd[r*34 + lane];
            out[16384 + (size_t)n*32 + lane] = x[(size_t)n*32 + lane] + mlpd[r*34 + 2 + lane];
            __syncthreads();
        }
    }
}

// ---------------------------------------------------------------------------
extern "C" void kernel_launch(void* const* d_in, const int* in_sizes, int n_in,
                              void* d_out, int out_size, void* d_ws, size_t ws_size,
                              hipStream_t stream) {
    const float* positions = (const float*)d_in[0];
    const float* weights   = (const float*)d_in[1];
    // d_in[2] = batch (int32) — unused, shapes static
    const float* kpos = (const float*)d_in[3];
    const float* kw   = (const float*)d_in[4];
    const float* cg_  = (const float*)d_in[5];
    const float* cb_  = (const float*)d_in[6];
    const float* W1   = (const float*)d_in[7];
    const float* b1   = (const float*)d_in[8];
    const float* bg   = (const float*)d_in[9];
    const float* bb   = (const float*)d_in[10];
    const float* W2   = (const float*)d_in[11];
    const float* b2   = (const float*)d_in[12];
    float* ws  = (float*)d_ws;
    float* out = (float*)d_out;

    // occupancy-derived cooperative grid (grid-stride phases accept any size)
    int nb = 0;
    int G = 256;
    if (hipOccupancyMaxActiveBlocksPerMultiprocessor(&nb, k_fused, 256, 0)
            == hipSuccess && nb > 0) {
        G = nb * 256;                 // 256 CUs on MI355X
        if (G > 1024) G = 1024;
    }

    int mode = -1;
    void* args[] = { &positions, &weights, &kpos, &kw, &cg_, &cb_,
                     &W1, &b1, &bg, &bb, &W2, &b2, &ws, &out, &mode };
    hipError_t err = hipLaunchCooperativeKernel((const void*)k_fused,
                                                dim3(G), dim3(256),
                                                args, 0, stream);
    if (err != hipSuccess) {
        (void)hipGetLastError();      // clear sticky error
        // fallback: 5 plain dispatches, same phased kernel
        k_fused<<<417, 256, 0, stream>>>(positions, weights, kpos, kw, cg_, cb_,
                                         W1, b1, bg, bb, W2, b2, ws, out, 0);
        k_fused<<<1024, 256, 0, stream>>>(positions, weights, kpos, kw, cg_, cb_,
                                          W1, b1, bg, bb, W2, b2, ws, out, 1);
        k_fused<<<1024, 256, 0, stream>>>(positions, weights, kpos, kw, cg_, cb_,
                                          W1, b1, bg, bb, W2, b2, ws, out, 2);
        k_fused<<<1024, 256, 0, stream>>>(positions, weights, kpos, kw, cg_, cb_,
                                          W1, b1, bg, bb, W2, b2, ws, out, 3);
        k_fused<<<1024, 256, 0, stream>>>(positions, weights, kpos, kw, cg_, cb_,
                                          W1, b1, bg, bb, W2, b2, ws, out, 4);
    }
}

// Round 7
// 195.085 us; speedup vs baseline: 2.4277x; 2.4277x over previous
//
#include <hip/hip_runtime.h>
#include <hip/hip_bf16.h>

// Problem constants
#define BB    8
#define NBB   1024
#define KK    9
#define CC    32
#define CMM   128
#define NTOT  (BB*NBB)        // 8192
#define MM    (NBB*KK)        // 9216 per batch
#define NEG   0.01f
#define EPS   1e-5f
#define L2C   (-2.8853900817779268f)   /* -2*log2(e) */

// Workspace layout (floats)
#define OFF_CWT   0
#define SZ_CWT    (BB*CC*MM/2)            // bf16 in float-slots: 1179648
#define OFF_CFX   (OFF_CWT + SZ_CWT)
#define OFF_CFY   (OFF_CFX + BB*MM)
#define OFF_CF0   (OFF_CFY + BB*MM)
#define OFF_X0    (OFF_CF0 + BB*MM)
#define OFF_X     (OFF_X0 + NTOT*CC)
#define OFF_H0    (OFF_X + NTOT*CC)
#define OFF_ST    (OFF_H0 + NTOT*CMM)     // s1r[4*64] then s2r[4*256] = 1280

typedef __attribute__((ext_vector_type(8))) short short8;
typedef __attribute__((ext_vector_type(4))) float f32x4;
typedef __attribute__((ext_vector_type(2))) float f32x2;

static __device__ __forceinline__ unsigned short f2bf_rne(float f) {
    __hip_bfloat16 h = __float2bfloat16(f);
    return *reinterpret_cast<unsigned short*>(&h);
}

// ---------------------------------------------------------------------------
// k_pc: blocks 0-127 convw (MFMA + LDS transpose), 128-415 Gaussian coefs,
//       416 zeroes the replicated stats accumulators. All independent.
// ---------------------------------------------------------------------------
__global__ __launch_bounds__(256) void k_pc(const float* __restrict__ pos,
                                            const float* __restrict__ kpos,
                                            const float* __restrict__ wts,
                                            const float* __restrict__ kw,
                                            short* __restrict__ cwT,
                                            float* __restrict__ cfx,
                                            float* __restrict__ cfy,
                                            float* __restrict__ cf0,
                                            float* __restrict__ stats) {
    __shared__ unsigned short tile[4*32*144];   // 36 KB (convw branch only)
    int u = blockIdx.x;
    int t = threadIdx.x;
    if (u < 128) {
        // conv_w[n][k][c] = sum_cp w[n][cp]*kw[k][cp][c] -> cwT[b][c][m] bf16
        int l = t & 63, wv = t >> 6;
        int lane15 = l & 15, quad = l >> 4;
        int b = u >> 4, nbl = u & 15;
        int n = b*NBB + nbl*64 + wv*16 + lane15;
        f32x4 w0 = *(const f32x4*)&wts[(size_t)n*CC + quad*8];
        f32x4 w1 = *(const f32x4*)&wts[(size_t)n*CC + quad*8 + 4];
        union { unsigned short us[8]; short8 s; } bfr;
        bfr.us[0] = f2bf_rne(w0.x); bfr.us[1] = f2bf_rne(w0.y);
        bfr.us[2] = f2bf_rne(w0.z); bfr.us[3] = f2bf_rne(w0.w);
        bfr.us[4] = f2bf_rne(w1.x); bfr.us[5] = f2bf_rne(w1.y);
        bfr.us[6] = f2bf_rne(w1.z); bfr.us[7] = f2bf_rne(w1.w);
        unsigned short* tw = tile + wv*4608;
        for (int kk = 0; kk < KK; ++kk) {
            #pragma unroll
            for (int ct = 0; ct < 2; ++ct) {
                int c = ct*16 + lane15;
                union { unsigned short us[8]; short8 s; } afr;
                #pragma unroll
                for (int j = 0; j < 8; ++j)
                    afr.us[j] = f2bf_rne(kw[(size_t)(kk*CC + quad*8 + j)*CC + c]);
                f32x4 acc = __builtin_amdgcn_mfma_f32_16x16x32_bf16(
                    afr.s, bfr.s, (f32x4)0.f, 0, 0, 0);
                #pragma unroll
                for (int reg = 0; reg < 4; ++reg) {
                    int cr = ct*16 + quad*4 + reg;
                    tw[cr*144 + lane15*9 + kk] = f2bf_rne(acc[reg]);
                }
            }
        }
        __syncthreads();
        short* dst = cwT + (size_t)b*CC*MM + (size_t)(nbl*64 + wv*16)*9;
        #pragma unroll
        for (int it = 0; it < 9; ++it) {
            int uu = it*64 + l;
            int c = uu / 18, seg = uu - c*18;
            short8 v = *(const short8*)&tw[c*144 + seg*8];
            *(short8*)&dst[(size_t)c*MM + seg*8] = v;
        }
    } else if (u < 416) {
        int gid = (u - 128)*256 + t;      // 0 .. 73727 = BB*MM
        int b = gid / MM;
        int m = gid - b*MM;
        int np = m / 9, k9 = m - np*9;
        float qx = pos[((size_t)(b*NBB + np))*2 + 0] + kpos[k9*2 + 0];
        float qy = pos[((size_t)(b*NBB + np))*2 + 1] + kpos[k9*2 + 1];
        cfx[gid] = -2.f*L2C*qx;
        cfy[gid] = -2.f*L2C*qy;
        cf0[gid] = L2C*(qx*qx + qy*qy);
    } else {
        for (int i = t; i < 1280; i += 256) stats[i] = 0.f;
    }
}

// ---------------------------------------------------------------------------
// k_sample2 (dominant, MFMA): block = 16 complete rows; 4 waves split the
// 9216-m range 4-ways; LDS reduce across waves; leaky + x0 + s1 atomics
// fused into the epilogue. grid = 8 b x 64 row-tiles = 512 blocks.
// ---------------------------------------------------------------------------
__global__ __launch_bounds__(256) void k_sample2(const float* __restrict__ pos,
                                                 const float* __restrict__ cfx,
                                                 const float* __restrict__ cfy,
                                                 const float* __restrict__ cf0,
                                                 const short* __restrict__ cwT,
                                                 float* __restrict__ x0,
                                                 float* __restrict__ s1r) {
    __shared__ float red[4*512];   // 8 KB: [wave][c*16 + n_loc]
    int t = threadIdx.x;
    int l = t & 63, w = t >> 6;
    int lane15 = l & 15, quad = l >> 4;
    int blk = blockIdx.x;
    int b = blk >> 6, nb = blk & 63;
    int nbase = b*NBB + nb*16;

    int n = nbase + lane15;
    float X = pos[(size_t)n*2], Y = pos[(size_t)n*2 + 1];
    float cn = L2C*(X*X + Y*Y);

    f32x4 acc0 = (f32x4)0.f, acc1 = (f32x4)0.f;
    const float* bx = cfx + (size_t)b*MM;
    const float* by = cfy + (size_t)b*MM;
    const float* b0 = cf0 + (size_t)b*MM;
    const short* ca0 = cwT + (size_t)b*CC*MM + (size_t)lane15*MM;
    const short* ca1 = ca0 + (size_t)16*MM;

    int m0 = w*(MM/4) + quad*8;
    #pragma unroll 2
    for (int kk = 0; kk < (MM/4)/32; ++kk, m0 += 32) {
        short8 a0 = *(const short8*)&ca0[m0];
        short8 a1 = *(const short8*)&ca1[m0];
        f32x4 vx0 = *(const f32x4*)&bx[m0];
        f32x4 vx1 = *(const f32x4*)&bx[m0 + 4];
        f32x4 vy0 = *(const f32x4*)&by[m0];
        f32x4 vy1 = *(const f32x4*)&by[m0 + 4];
        f32x4 v00 = *(const f32x4*)&b0[m0];
        f32x4 v01 = *(const f32x4*)&b0[m0 + 4];
        f32x2 Xv = {X, X}, Yv = {Y, Y}, Cv = {cn, cn};
        f32x2 t0 = (f32x2){v00.x, v00.y} + Cv;
        t0 = (f32x2){vy0.x, vy0.y}*Yv + t0;
        t0 = (f32x2){vx0.x, vx0.y}*Xv + t0;
        f32x2 t1 = (f32x2){v00.z, v00.w} + Cv;
        t1 = (f32x2){vy0.z, vy0.w}*Yv + t1;
        t1 = (f32x2){vx0.z, vx0.w}*Xv + t1;
        f32x2 t2 = (f32x2){v01.x, v01.y} + Cv;
        t2 = (f32x2){vy1.x, vy1.y}*Yv + t2;
        t2 = (f32x2){vx1.x, vx1.y}*Xv + t2;
        f32x2 t3 = (f32x2){v01.z, v01.w} + Cv;
        t3 = (f32x2){vy1.z, vy1.w}*Yv + t3;
        t3 = (f32x2){vx1.z, vx1.w}*Xv + t3;
        float e0 = __builtin_amdgcn_exp2f(t0.x);
        float e1 = __builtin_amdgcn_exp2f(t0.y);
        float e2 = __builtin_amdgcn_exp2f(t1.x);
        float e3 = __builtin_amdgcn_exp2f(t1.y);
        float e4 = __builtin_amdgcn_exp2f(t2.x);
        float e5 = __builtin_amdgcn_exp2f(t2.y);
        float e6 = __builtin_amdgcn_exp2f(t3.x);
        float e7 = __builtin_amdgcn_exp2f(t3.y);
        union { unsigned int uu[4]; short8 s; } bf;
        bf.uu[0] = (__float_as_uint(e0) >> 16) | (__float_as_uint(e1) & 0xffff0000u);
        bf.uu[1] = (__float_as_uint(e2) >> 16) | (__float_as_uint(e3) & 0xffff0000u);
        bf.uu[2] = (__float_as_uint(e4) >> 16) | (__float_as_uint(e5) & 0xffff0000u);
        bf.uu[3] = (__float_as_uint(e6) >> 16) | (__float_as_uint(e7) & 0xffff0000u);
        acc0 = __builtin_amdgcn_mfma_f32_16x16x32_bf16(a0, bf.s, acc0, 0, 0, 0);
        acc1 = __builtin_amdgcn_mfma_f32_16x16x32_bf16(a1, bf.s, acc1, 0, 0, 0);
    }
    // stash wave accumulators: D col(n)=lane15, row(c)=quad*4+reg (+16 for acc1)
    #pragma unroll
    for (int reg = 0; reg < 4; ++reg) {
        red[w*512 + (quad*4 + reg)*16 + lane15]      = acc0[reg];
        red[w*512 + (16 + quad*4 + reg)*16 + lane15] = acc1[reg];
    }
    __syncthreads();
    // cross-wave reduce: thread t handles tile positions t (c=t>>4) and t+256
    float v0 = red[t] + red[512 + t] + red[1024 + t] + red[1536 + t];
    float v1 = red[256 + t] + red[768 + t] + red[1280 + t] + red[1792 + t];
    v0 = v0 >= 0.f ? v0 : NEG*v0;
    v1 = v1 >= 0.f ? v1 : NEG*v1;
    int c0 = t >> 4, nl = t & 15;
    x0[(size_t)(nbase + nl)*CC + c0]      = v0;
    x0[(size_t)(nbase + nl)*CC + c0 + 16] = v1;
    // s1 stats: shfl-reduce over the 16-lane n-groups (same c per group)
    float s0 = v0, q0 = v0*v0, s1_ = v1, q1 = v1*v1;
    #pragma unroll
    for (int off = 1; off < 16; off <<= 1) {
        s0 += __shfl_xor(s0, off, 16);
        q0 += __shfl_xor(q0, off, 16);
        s1_ += __shfl_xor(s1_, off, 16);
        q1 += __shfl_xor(q1, off, 16);
    }
    if (nl == 0) {
        float* dst = s1r + (blk & 3)*64;
        atomicAdd(&dst[c0], s0);
        atomicAdd(&dst[32 + c0], q0);
        atomicAdd(&dst[c0 + 16], s1_);
        atomicAdd(&dst[32 + c0 + 16], q1);
    }
}

// ---------------------------------------------------------------------------
// k_mlp1: x = bn1(x0) + weights; h0 = leaky(x @ W1 + b1); replicated s2.
// grid = 1024, 8 rows/block.
// ---------------------------------------------------------------------------
__global__ __launch_bounds__(256) void k_mlp1(const float* __restrict__ x0,
                                              const float* __restrict__ wts,
                                              const float* __restrict__ gma,
                                              const float* __restrict__ bta,
                                              const float* __restrict__ W1,
                                              const float* __restrict__ b1,
                                              const float* __restrict__ s1r,
                                              float* __restrict__ x,
                                              float* __restrict__ h0,
                                              float* __restrict__ s2r) {
    __shared__ float xrow[256];   // 8 rows x 32 c
    __shared__ float st2[256];
    int t = threadIdx.x;
    int r = t >> 5, c = t & 31;
    int n0 = blockIdx.x*8;
    {
        int n = n0 + r;
        float su = s1r[c]      + s1r[64 + c]  + s1r[128 + c] + s1r[192 + c];
        float sq = s1r[32 + c] + s1r[96 + c]  + s1r[160 + c] + s1r[224 + c];
        float mu  = su * (1.f/NTOT);
        float var = sq * (1.f/NTOT) - mu*mu;
        float a   = gma[c] * rsqrtf(var + EPS);
        float v   = x0[(size_t)n*CC + c];
        v = a*(v - mu) + bta[c] + wts[(size_t)n*CC + c];
        xrow[r*32 + c] = v;
        x[(size_t)n*CC + c] = v;
    }
    st2[t] = 0.f;
    __syncthreads();
    int j = t & 127, rh = t >> 7;
    float acc4[4];
    #pragma unroll
    for (int q = 0; q < 4; ++q) acc4[q] = b1[j];
    #pragma unroll 4
    for (int cc2 = 0; cc2 < 32; ++cc2) {
        float w1c = W1[cc2*CMM + j];      // coalesced across lanes
        #pragma unroll
        for (int q = 0; q < 4; ++q)
            acc4[q] = fmaf(xrow[(rh*4 + q)*32 + cc2], w1c, acc4[q]);
    }
    float ls = 0.f, lq = 0.f;
    #pragma unroll
    for (int q = 0; q < 4; ++q) {
        float h = acc4[q] >= 0.f ? acc4[q] : NEG*acc4[q];
        h0[(size_t)(n0 + rh*4 + q)*CMM + j] = h;
        ls += h; lq = fmaf(h, h, lq);
    }
    atomicAdd(&st2[j], ls);
    atomicAdd(&st2[128 + j], lq);
    __syncthreads();
    atomicAdd(&s2r[(blockIdx.x & 3)*256 + t], st2[t]);
}

// ---------------------------------------------------------------------------
// k_mlp2: h = bn2(h0); mlp = h @ W2 + b2; out0 = pos + mlp[:,:2];
//         out1 = x + mlp[:,2:]. grid = 1024, 8 rows/block.
// ---------------------------------------------------------------------------
__global__ __launch_bounds__(256) void k_mlp2(const float* __restrict__ h0,
                                              const float* __restrict__ x,
                                              const float* __restrict__ pos,
                                              const float* __restrict__ g2,
                                              const float* __restrict__ bt2,
                                              const float* __restrict__ W2,
                                              const float* __restrict__ b2v,
                                              const float* __restrict__ s2r,
                                              float* __restrict__ out) {
    __shared__ float hl[8*132];
    __shared__ float mlpd[8*34];
    int t = threadIdx.x;
    int n0 = blockIdx.x*8;
    #pragma unroll
    for (int i = 0; i < 4; ++i) {
        int idx = i*256 + t;
        int j = idx & 127, r = idx >> 7;
        float su = s2r[j]       + s2r[256 + j] + s2r[512 + j] + s2r[768 + j];
        float sq = s2r[128 + j] + s2r[384 + j] + s2r[640 + j] + s2r[896 + j];
        float mu  = su * (1.f/NTOT);
        float var = sq * (1.f/NTOT) - mu*mu;
        float a   = g2[j] * rsqrtf(var + EPS);
        float v = h0[(size_t)(n0 + r)*CMM + j];
        hl[r*132 + j] = a*(v - mu) + bt2[j];
    }
    __syncthreads();
    int r = t >> 5, lane = t & 31;
    float acc0 = b2v[lane];
    float acc1 = (lane < 2) ? b2v[32 + lane] : 0.f;
    for (int j = 0; j < CMM; ++j) {
        float h = hl[r*132 + j];
        acc0 = fmaf(h, W2[(size_t)j*34 + lane], acc0);
        if (lane < 2) acc1 = fmaf(h, W2[(size_t)j*34 + 32 + lane], acc1);
    }
    mlpd[r*34 + lane] = acc0;
    if (lane < 2) mlpd[r*34 + 32 + lane] = acc1;
    __syncthreads();
    int n = n0 + r;
    if (lane < 2)
        out[(size_t)n*2 + lane] = pos[(size_t)n*2 + lane] + mlpd[r*34 + lane];
    out[16384 + (size_t)n*32 + lane] = x[(size_t)n*32 + lane] + mlpd[r*34 + 2 + lane];
}

// ---------------------------------------------------------------------------
extern "C" void kernel_launch(void* const* d_in, const int* in_sizes, int n_in,
                              void* d_out, int out_size, void* d_ws, size_t ws_size,
                              hipStream_t stream) {
    const float* positions = (const float*)d_in[0];
    const float* weights   = (const float*)d_in[1];
    // d_in[2] = batch (int32) — unused, shapes static
    const float* kpos = (const float*)d_in[3];
    const float* kw   = (const float*)d_in[4];
    const float* cg_  = (const float*)d_in[5];
    const float* cb_  = (const float*)d_in[6];
    const float* W1   = (const float*)d_in[7];
    const float* b1   = (const float*)d_in[8];
    const float* bg   = (const float*)d_in[9];
    const float* bb   = (const float*)d_in[10];
    const float* W2   = (const float*)d_in[11];
    const float* b2   = (const float*)d_in[12];
    float* ws  = (float*)d_ws;
    float* out = (float*)d_out;

    short* cwT = (short*)(ws + OFF_CWT);
    float* s1r = ws + OFF_ST;          // 4 x 64
    float* s2r = ws + OFF_ST + 256;    // 4 x 256

    k_pc<<<417, 256, 0, stream>>>(positions, kpos, weights, kw, cwT,
                                  ws + OFF_CFX, ws + OFF_CFY, ws + OFF_CF0,
                                  ws + OFF_ST);
    k_sample2<<<512, 256, 0, stream>>>(positions, ws + OFF_CFX, ws + OFF_CFY,
                                       ws + OFF_CF0, cwT, ws + OFF_X0, s1r);
    k_mlp1<<<1024, 256, 0, stream>>>(ws + OFF_X0, weights, cg_, cb_, W1, b1,
                                     s1r, ws + OFF_X, ws + OFF_H0, s2r);
    k_mlp2<<<1024, 256, 0, stream>>>(ws + OFF_H0, ws + OFF_X, positions,
                                     bg, bb, W2, b2, s2r, out);
}